// Round 7
// baseline (787.522 us; speedup 1.0000x reference)
//
#include <hip/hip_runtime.h>
#include <hip/hip_bf16.h>

#define N_NODES 100000
#define N_PAD   100096   // padded to multiple of 128
#define N_EDGES 1600000
#define NXCD    8
#define NRANGE  ((N_NODES + NXCD - 1) / NXCD)   // 12500
#define NSLICE  256

typedef __bf16 bf16x8 __attribute__((ext_vector_type(8)));
typedef float  f32x4  __attribute__((ext_vector_type(4)));

__device__ __forceinline__ void gload16(const void* g, void* s) {
    __builtin_amdgcn_global_load_lds(
        (const __attribute__((address_space(1))) unsigned int*)g,
        (__attribute__((address_space(3))) unsigned int*)s, 16, 0, 0);
}

// unpack a uint holding two bf16 (x = low ushort = even col, y = high = odd col)
__device__ __forceinline__ float2 bf2f(unsigned p) {
    float2 r;
    union { unsigned u; float f; } a, b;
    a.u = p << 16;
    b.u = p & 0xffff0000u;
    r.x = a.f; r.y = b.f;
    return r;
}
__device__ __forceinline__ unsigned f2bf2(float x, float y) {
    unsigned lo = (unsigned)__builtin_bit_cast(unsigned short, __float2bfloat16(x));
    unsigned hi = (unsigned)__builtin_bit_cast(unsigned short, __float2bfloat16(y));
    return lo | (hi << 16);
}

// ---------------------------------------------------------------------------
// Edge-index width detection (int64 vs int32 layout in the buffer).
// ---------------------------------------------------------------------------
__global__ void detect_kernel(const unsigned* __restrict__ e, int* __restrict__ flag) {
    __shared__ int nz;
    if (threadIdx.x == 0) nz = 0;
    __syncthreads();
    int local = 0;
    for (int i = threadIdx.x; i < 1024; i += blockDim.x)
        if (e[2 * i + 1] != 0) local = 1;
    if (local) atomicOr(&nz, 1);
    __syncthreads();
    if (threadIdx.x == 0) *flag = (nz == 0) ? 1 : 0;
}

__device__ __forceinline__ int edge_at(const unsigned* __restrict__ e, long idx, int is64) {
    return (int)(is64 ? e[2 * idx] : e[idx]);
}

__global__ void hist_kernel(const unsigned* __restrict__ e, const int* __restrict__ flag,
                            int* __restrict__ counts) {
    int i = blockIdx.x * blockDim.x + threadIdx.x;
    if (i >= N_EDGES) return;
    int is64 = *flag;
    int d = edge_at(e, (long)N_EDGES + i, is64);
    atomicAdd(&counts[d], 1);
}

__global__ void scan1_kernel(const int* __restrict__ counts, int* __restrict__ blockSums) {
    __shared__ int red[256];
    int base = blockIdx.x * 1024;
    int sum = 0;
    for (int i = threadIdx.x; i < 1024; i += 256) {
        int idx = base + i;
        sum += (idx < N_NODES) ? counts[idx] : 0;
    }
    red[threadIdx.x] = sum;
    __syncthreads();
    for (int s = 128; s > 0; s >>= 1) {
        if (threadIdx.x < s) red[threadIdx.x] += red[threadIdx.x + s];
        __syncthreads();
    }
    if (threadIdx.x == 0) blockSums[blockIdx.x] = red[0];
}

__global__ void scan2_kernel(int* __restrict__ blockSums, int nb, int* __restrict__ row_ptr) {
    int run = 0;
    for (int i = 0; i < nb; ++i) { int v = blockSums[i]; blockSums[i] = run; run += v; }
    row_ptr[N_NODES] = run;
}

__global__ void scan3_kernel(const int* __restrict__ counts, const int* __restrict__ blockSums,
                             int* __restrict__ row_ptr, int* __restrict__ cursor,
                             float* __restrict__ deg_inv) {
    __shared__ int lds[256];
    int base = blockIdx.x * 1024;
    int t = threadIdx.x;
    int v[4];
    int s = 0;
    for (int i = 0; i < 4; ++i) {
        int idx = base + t * 4 + i;
        v[i] = (idx < N_NODES) ? counts[idx] : 0;
        s += v[i];
    }
    lds[t] = s;
    __syncthreads();
    for (int off = 1; off < 256; off <<= 1) {
        int add = (t >= off) ? lds[t - off] : 0;
        __syncthreads();
        lds[t] += add;
        __syncthreads();
    }
    int excl = lds[t] - s + blockSums[blockIdx.x];
    for (int i = 0; i < 4; ++i) {
        int idx = base + t * 4 + i;
        if (idx < N_NODES) {
            row_ptr[idx] = excl;
            cursor[idx]  = excl;
            deg_inv[idx] = 1.0f / fmaxf((float)v[i], 1.0f);
            excl += v[i];
        }
    }
}

// ---------------------------------------------------------------------------
// fill v2: XCD-range-partitioned CSR scatter (full-line writebacks in one L2).
// ---------------------------------------------------------------------------
__global__ __launch_bounds__(256) void fill2_kernel(
    const unsigned* __restrict__ e, const int* __restrict__ flag,
    int* __restrict__ cursor, int* __restrict__ csr_src) {
    const int r     = blockIdx.x & (NXCD - 1);
    const int slice = blockIdx.x >> 3;
    const int lo = r * NRANGE;
    const int hi = min(lo + NRANGE, N_NODES);
    const int is64 = *flag;
    const int per = (N_EDGES + NSLICE - 1) / NSLICE;  // 6250
    const int i0 = slice * per;
    const int i1 = min(i0 + per, N_EDGES);
    for (int i = i0 + (int)threadIdx.x; i < i1; i += 256) {
        int d = edge_at(e, (long)N_EDGES + i, is64);
        if (d >= lo && d < hi) {
            int s = edge_at(e, (long)i, is64);
            int pos = atomicAdd(&cursor[d], 1);
            csr_src[pos] = s;
        }
    }
}

// ---------------------------------------------------------------------------
// Weight prep: BtAll[layer][768 rows][128 k] bf16, k-contiguous.
// Rows 0..383   (main):  n<128 -> W_lin col n ; n<384 -> W_film col n-128.
// Rows 384..767 (skip, PERMUTED in groups of 16):
//   rr=row-384, g=rr/16, within=rr%16, kind=g%3, c=(g/3)*16+within
//   kind 0 -> W_skip[:,c]; 1 -> W_fskip[:,c] (beta_s); 2 -> W_fskip[:,128+c] (gamma_s)
// ---------------------------------------------------------------------------
__global__ void bt_prep_kernel(const float* __restrict__ Wl, const float* __restrict__ Wf,
                               const float* __restrict__ Ws, const float* __restrict__ Wfs,
                               __hip_bfloat16* __restrict__ Bt) {
    int idx = blockIdx.x * 256 + threadIdx.x;
    if (idx >= 4 * 768 * 128) return;
    int k   = idx % 128;
    int row = (idx / 128) % 768;
    int lay = idx / (128 * 768);
    float w;
    if (row < 128) {
        w = Wl[(size_t)lay * 16384 + k * 128 + row];
    } else if (row < 384) {
        w = Wf[(size_t)lay * 32768 + k * 256 + (row - 128)];
    } else {
        int rr = row - 384;
        int g = rr >> 4, within = rr & 15;
        int kind = g % 3;
        int c = (g / 3) * 16 + within;
        if (kind == 0)      w = Ws [(size_t)lay * 16384 + k * 128 + c];
        else if (kind == 1) w = Wfs[(size_t)lay * 32768 + k * 256 + c];
        else                w = Wfs[(size_t)lay * 32768 + k * 256 + 128 + c];
    }
    Bt[idx] = __float2bfloat16(w);
}

// x (f32) -> A bf16 [node][128] (packed pairs)
__global__ void cast_kernel(const float* __restrict__ x, unsigned* __restrict__ A2) {
    long i = (long)blockIdx.x * 256 + threadIdx.x;
    if (i >= (long)N_NODES * 64) return;
    float2 v = ((const float2*)x)[i];
    A2[i] = f2bf2(v.x, v.y);
}

// ---------------------------------------------------------------------------
// Layer GEMM v2: ONE block per 128-node m-tile computes ALL 768 output cols.
// A (128x128, 32KB) staged once, all 16 A-fragments cached in VGPRs; the 7
// B-chunks (3 main 128-wide + 4 skip 96-wide) are staged sequentially into a
// single 32KB LDS buffer, epilogue of chunk c overlapped with stage of c+1.
// Removes the 7x redundant A re-read of the previous n-tile-parallel version.
// ---------------------------------------------------------------------------
__global__ __launch_bounds__(256, 2) void layer_gemm_kernel(
    const __hip_bfloat16* __restrict__ A,
    const __hip_bfloat16* __restrict__ Bt,   // this layer, all 768 rows x 128 k
    const float* __restrict__ bfilm,
    __hip_bfloat16* __restrict__ hbuf,       // [N][128]
    __hip_bfloat16* __restrict__ bgbuf,      // [N][256]
    __hip_bfloat16* __restrict__ skbh)       // [N][128] bf16 (relu'd skip)
{
    __shared__ alignas(16) unsigned char ldsA[32768];
    __shared__ alignas(16) unsigned char ldsB[32768];

    const int t = threadIdx.x;
    const long node0 = (long)blockIdx.x * 128;
    const int w  = t >> 6, l = t & 63;
    const int wm = w >> 1, wn = w & 1;
    const int lr = l & 15;
    const int kq16 = (l >> 4) << 4;
    const int sw = (lr & 7) << 4;

    const int srow = t >> 4;                  // staging row within 16-row pass
    const int scol = (t & 15) << 4;           // staging col-byte (0..240)
    const int scbs = scol ^ ((srow & 7) << 4);// source-side inverse swizzle

    const char* Abase = (const char*)A;
    const char* Bbase = (const char*)Bt;

    auto stageB = [&](int rowbase, int passes) {
        for (int i = 0; i < passes; ++i)
            gload16(Bbase + (size_t)(rowbase + (i << 4) + srow) * 256 + scbs,
                    ldsB + (i << 12) + t * 16);
    };

    // stage A once + first B chunk
    #pragma unroll
    for (int i = 0; i < 8; ++i)
        gload16(Abase + (node0 + (i << 4) + srow) * 256 + scbs,
                ldsA + (i << 12) + t * 16);
    stageB(0, 8);
    __syncthreads();

    // cache all A fragments: af[kh][mi], kh = k-quarter of 32, mi = m-frag
    bf16x8 af[4][4];
    #pragma unroll
    for (int kh = 0; kh < 4; ++kh)
        #pragma unroll
        for (int mi = 0; mi < 4; ++mi)
            af[kh][mi] = *(const bf16x8*)(
                ldsA + (wm * 64 + mi * 16 + lr) * 256 + (((kh << 6) + kq16) ^ sw));

    const int col = lr;
    const int rb  = (l >> 4) << 2;

    // ---------------- main chunks: c = 0 (h), 1, 2 (beta|gamma) -----------
    for (int c = 0; c < 3; ++c) {
        f32x4 acc[4][4];
        #pragma unroll
        for (int mi = 0; mi < 4; ++mi)
            #pragma unroll
            for (int ni = 0; ni < 4; ++ni)
                #pragma unroll
                for (int j = 0; j < 4; ++j) acc[mi][ni][j] = 0.f;

        #pragma unroll
        for (int kh = 0; kh < 4; ++kh) {
            const int kbs = ((kh << 6) + kq16) ^ sw;
            bf16x8 bfr[4];
            #pragma unroll
            for (int ni = 0; ni < 4; ++ni)
                bfr[ni] = *(const bf16x8*)(ldsB + (wn * 64 + ni * 16 + lr) * 256 + kbs);
            #pragma unroll
            for (int mi = 0; mi < 4; ++mi)
                #pragma unroll
                for (int ni = 0; ni < 4; ++ni)
                    acc[mi][ni] = __builtin_amdgcn_mfma_f32_16x16x32_bf16(
                        af[kh][mi], bfr[ni], acc[mi][ni], 0, 0, 0);
        }
        __syncthreads();                       // done reading B(c)
        if (c < 2) stageB((c + 1) * 128, 8);   // issue next main chunk
        else       stageB(384, 6);             // issue first skip chunk

        if (c == 0) {
            #pragma unroll
            for (int mi = 0; mi < 4; ++mi)
                #pragma unroll
                for (int ni = 0; ni < 4; ++ni) {
                    const int n = wn * 64 + ni * 16 + col;
                    #pragma unroll
                    for (int j = 0; j < 4; ++j) {
                        long node = node0 + wm * 64 + mi * 16 + rb + j;
                        if (node < N_NODES)
                            hbuf[node * 128 + n] = __float2bfloat16(acc[mi][ni][j]);
                    }
                }
        } else {
            const int c0 = (c - 1) * 128;
            #pragma unroll
            for (int mi = 0; mi < 4; ++mi)
                #pragma unroll
                for (int ni = 0; ni < 4; ++ni) {
                    const int n = wn * 64 + ni * 16 + col;
                    const float bb = bfilm[c0 + n];
                    #pragma unroll
                    for (int j = 0; j < 4; ++j) {
                        long node = node0 + wm * 64 + mi * 16 + rb + j;
                        if (node < N_NODES)
                            bgbuf[node * 256 + c0 + n] = __float2bfloat16(acc[mi][ni][j] + bb);
                    }
                }
        }
        __syncthreads();                       // next B chunk landed
    }

    // ---------------- skip chunks: j2 = 0..3 (96-wide, fused FiLM) --------
    for (int j2 = 0; j2 < 4; ++j2) {
        f32x4 acc[4][3];
        #pragma unroll
        for (int mi = 0; mi < 4; ++mi)
            #pragma unroll
            for (int ni = 0; ni < 3; ++ni)
                #pragma unroll
                for (int j = 0; j < 4; ++j) acc[mi][ni][j] = 0.f;

        #pragma unroll
        for (int kh = 0; kh < 4; ++kh) {
            const int kbs = ((kh << 6) + kq16) ^ sw;
            bf16x8 bfr[3];
            #pragma unroll
            for (int ni = 0; ni < 3; ++ni)
                bfr[ni] = *(const bf16x8*)(ldsB + (wn * 48 + ni * 16 + lr) * 256 + kbs);
            #pragma unroll
            for (int mi = 0; mi < 4; ++mi)
                #pragma unroll
                for (int ni = 0; ni < 3; ++ni)
                    acc[mi][ni] = __builtin_amdgcn_mfma_f32_16x16x32_bf16(
                        af[kh][mi], bfr[ni], acc[mi][ni], 0, 0, 0);
        }
        __syncthreads();                        // done reading this skip chunk
        if (j2 < 3) stageB(384 + (j2 + 1) * 96, 6);

        // fused epilogue: ni 0=sk, 1=bs, 2=gs for the SAME column c
        const int cc = (2 * j2 + wn) * 16 + lr;
        #pragma unroll
        for (int mi = 0; mi < 4; ++mi)
            #pragma unroll
            for (int j = 0; j < 4; ++j) {
                long node = node0 + wm * 64 + mi * 16 + rb + j;
                if (node < N_NODES) {
                    float o = fmaxf(acc[mi][2][j] * acc[mi][0][j] + acc[mi][1][j], 0.f);
                    skbh[node * 128 + cc] = __float2bfloat16(o);
                }
            }
        if (j2 < 3) __syncthreads();
    }
}

// ---------------------------------------------------------------------------
// Aggregation v4: 1 wave per node; lane owns 4 cols (uint2 = 8 B gather);
// half-waves process two edges per gather instruction; 8 pairs unrolled
// (16 edges / 8 gathers in flight — covers a typical deg-16 node in one pass).
// ---------------------------------------------------------------------------
__global__ __launch_bounds__(256) void agg_kernel(
    const uint2* __restrict__ h22,      // hbuf  as [N][32] uint2
    const uint2* __restrict__ bgu2,     // bgbuf as [N][64] uint2 (beta 0..31 | gamma 32..63)
    const int* __restrict__ row_ptr, const int* __restrict__ csr_src,
    const float* __restrict__ deg_inv,
    const uint2* __restrict__ sku2,     // skb as [N][32] uint2 (bf16, relu'd)
    uint2* __restrict__ An2,            // next A as [N][32] uint2 (bf16)
    float4* __restrict__ fo4)           // final out as [N][32] float4
{
    const int t = threadIdx.x;
    const int v = blockIdx.x * 4 + (t >> 6);
    const int l = t & 63;
    const int half = l >> 5;
    const unsigned c = l & 31;

    const uint2 bu = bgu2[(size_t)v * 64 + c];
    const uint2 gu = bgu2[(size_t)v * 64 + 32 + c];
    const float2 be01 = bf2f(bu.x), be23 = bf2f(bu.y);
    const float2 ga01 = bf2f(gu.x), ga23 = bf2f(gu.y);
    const float dinv = deg_inv[v];

    const int b = row_ptr[v];
    const int e = row_ptr[v + 1];
    const int ne = e - b;
    const int npair = ne >> 1;

    f32x4 ac0 = {0,0,0,0}, ac1 = {0,0,0,0}, ac2 = {0,0,0,0}, ac3 = {0,0,0,0};

    const int* cp = csr_src + b + half;   // this lane's edge stream (stride 2)

#define ACC(A_, P_) do {                                   \
        float2 h01 = bf2f((P_).x), h23 = bf2f((P_).y);     \
        (A_)[0] += fmaxf(ga01.x * h01.x + be01.x, 0.f);    \
        (A_)[1] += fmaxf(ga01.y * h01.y + be01.y, 0.f);    \
        (A_)[2] += fmaxf(ga23.x * h23.x + be23.x, 0.f);    \
        (A_)[3] += fmaxf(ga23.y * h23.y + be23.y, 0.f);    \
    } while (0)

    int pi = 0;
    for (; pi + 8 <= npair; pi += 8) {
        unsigned s[8];
        uint2 p[8];
        #pragma unroll
        for (int u = 0; u < 8; ++u) s[u] = (unsigned)cp[2 * (pi + u)];
        #pragma unroll
        for (int u = 0; u < 8; ++u) p[u] = h22[s[u] * 32u + c];
        ACC(ac0, p[0]); ACC(ac1, p[1]); ACC(ac2, p[2]); ACC(ac3, p[3]);
        ACC(ac0, p[4]); ACC(ac1, p[5]); ACC(ac2, p[6]); ACC(ac3, p[7]);
    }
    for (; pi + 4 <= npair; pi += 4) {
        unsigned s[4];
        uint2 p[4];
        #pragma unroll
        for (int u = 0; u < 4; ++u) s[u] = (unsigned)cp[2 * (pi + u)];
        #pragma unroll
        for (int u = 0; u < 4; ++u) p[u] = h22[s[u] * 32u + c];
        ACC(ac0, p[0]); ACC(ac1, p[1]); ACC(ac2, p[2]); ACC(ac3, p[3]);
    }
    for (; pi < npair; ++pi) {
        const unsigned s0 = (unsigned)cp[2 * pi];
        const uint2 p0 = h22[s0 * 32u + c];
        ACC(ac0, p0);
    }
    if ((ne & 1) && half == 0) {
        const unsigned s0 = (unsigned)csr_src[e - 1];
        const uint2 p0 = h22[s0 * 32u + c];
        ACC(ac1, p0);
    }
#undef ACC

    float r0 = (ac0[0] + ac1[0]) + (ac2[0] + ac3[0]);
    float r1 = (ac0[1] + ac1[1]) + (ac2[1] + ac3[1]);
    float r2 = (ac0[2] + ac1[2]) + (ac2[2] + ac3[2]);
    float r3 = (ac0[3] + ac1[3]) + (ac2[3] + ac3[3]);
    r0 += __shfl_xor(r0, 32);
    r1 += __shfl_xor(r1, 32);
    r2 += __shfl_xor(r2, 32);
    r3 += __shfl_xor(r3, 32);

    const uint2 sk = sku2[(size_t)v * 32 + c];
    const float2 s01 = bf2f(sk.x), s23 = bf2f(sk.y);
    const float o0 = s01.x + r0 * dinv;
    const float o1 = s01.y + r1 * dinv;
    const float o2 = s23.x + r2 * dinv;
    const float o3 = s23.y + r3 * dinv;

    if (half == 0) {
        if (An2) {
            An2[(size_t)v * 32 + c] = make_uint2(f2bf2(o0, o1), f2bf2(o2, o3));
        } else {
            fo4[(size_t)v * 32 + c] = make_float4(o0, o1, o2, o3);
        }
    }
}

// ---------------------------------------------------------------------------
extern "C" void kernel_launch(void* const* d_in, const int* in_sizes, int n_in,
                              void* d_out, int out_size, void* d_ws, size_t ws_size,
                              hipStream_t stream) {
    const float*    x_in    = (const float*)d_in[0];
    const unsigned* eidx    = (const unsigned*)d_in[1];
    const float*    W_lin   = (const float*)d_in[2];
    const float*    W_film  = (const float*)d_in[3];
    const float*    b_film  = (const float*)d_in[4];
    const float*    W_skip  = (const float*)d_in[5];
    const float*    W_fskip = (const float*)d_in[6];
    float*          out     = (float*)d_out;

    char* ws = (char*)d_ws;
    size_t off = 0;
    auto alloc = [&](size_t bytes) -> void* {
        void* p = ws + off;
        off = (off + bytes + 255) & ~(size_t)255;
        return p;
    };
    int*   flag      = (int*)alloc(4);
    int*   counts    = (int*)alloc((size_t)N_NODES * 4);
    int*   row_ptr   = (int*)alloc((size_t)(N_NODES + 1) * 4);
    int*   cursor    = (int*)alloc((size_t)N_NODES * 4);
    int*   blockSums = (int*)alloc(128 * 4);
    float* deg_inv   = (float*)alloc((size_t)N_NODES * 4);
    int*   csr_src   = (int*)alloc((size_t)N_EDGES * 4);
    __hip_bfloat16* Abuf  = (__hip_bfloat16*)alloc((size_t)N_PAD * 128 * 2);
    __hip_bfloat16* BtAll = (__hip_bfloat16*)alloc((size_t)4 * 768 * 128 * 2);
    __hip_bfloat16* hbuf  = (__hip_bfloat16*)alloc((size_t)N_NODES * 128 * 2);
    __hip_bfloat16* bgbuf = (__hip_bfloat16*)alloc((size_t)N_NODES * 256 * 2);
    __hip_bfloat16* skbh  = (__hip_bfloat16*)alloc((size_t)N_NODES * 128 * 2);
    (void)ws_size; (void)in_sizes; (void)n_in; (void)out_size;

    const int NB_SCAN = (N_NODES + 1023) / 1024; // 98
    const int EB = (N_EDGES + 255) / 256;        // 6250

    hipMemsetAsync(counts, 0, (size_t)N_NODES * 4, stream);
    detect_kernel<<<1, 256, 0, stream>>>(eidx, flag);
    hist_kernel<<<EB, 256, 0, stream>>>(eidx, flag, counts);
    scan1_kernel<<<NB_SCAN, 256, 0, stream>>>(counts, blockSums);
    scan2_kernel<<<1, 1, 0, stream>>>(blockSums, NB_SCAN, row_ptr);
    scan3_kernel<<<NB_SCAN, 256, 0, stream>>>(counts, blockSums, row_ptr, cursor, deg_inv);
    fill2_kernel<<<NXCD * NSLICE, 256, 0, stream>>>(eidx, flag, cursor, csr_src);

    cast_kernel<<<(N_NODES * 64 + 255) / 256, 256, 0, stream>>>(x_in, (unsigned*)Abuf);
    bt_prep_kernel<<<(4 * 768 * 128 + 255) / 256, 256, 0, stream>>>(
        W_lin, W_film, W_skip, W_fskip, BtAll);

    const int MT = N_PAD / 128; // 782
    const int AGG_B = N_NODES / 4; // 25000
    for (int l = 0; l < 4; ++l) {
        const __hip_bfloat16* Bt_l = BtAll + (size_t)l * 768 * 128;
        layer_gemm_kernel<<<MT, 256, 0, stream>>>(
            Abuf, Bt_l, b_film + (size_t)l * 256, hbuf, bgbuf, skbh);
        agg_kernel<<<AGG_B, 256, 0, stream>>>(
            (const uint2*)hbuf, (const uint2*)bgbuf,
            row_ptr, csr_src, deg_inv, (const uint2*)skbh,
            (l < 3) ? (uint2*)Abuf : (uint2*)nullptr,
            (l == 3) ? (float4*)out : (float4*)nullptr);
    }
}

// Round 8
// 615.708 us; speedup vs baseline: 1.2791x; 1.2791x over previous
//
#include <hip/hip_runtime.h>
#include <hip/hip_bf16.h>

#define N_NODES 100000
#define N_PAD   100096   // padded to multiple of 128
#define N_EDGES 1600000
#define NXCD    8
#define NRANGE  ((N_NODES + NXCD - 1) / NXCD)   // 12500
#define NSLICE  256
#define MTILES  (N_PAD / 128)                   // 782
#define MTQ     ((MTILES + 7) / 8)              // 98
#define GEMM_GRID (8 * 7 * MTQ)                 // 5488

typedef __bf16 bf16x8 __attribute__((ext_vector_type(8)));
typedef float  f32x4  __attribute__((ext_vector_type(4)));

__device__ __forceinline__ void gload16(const void* g, void* s) {
    __builtin_amdgcn_global_load_lds(
        (const __attribute__((address_space(1))) unsigned int*)g,
        (__attribute__((address_space(3))) unsigned int*)s, 16, 0, 0);
}

// unpack a uint holding two bf16 (x = low ushort = even col, y = high = odd col)
__device__ __forceinline__ float2 bf2f(unsigned p) {
    float2 r;
    union { unsigned u; float f; } a, b;
    a.u = p << 16;
    b.u = p & 0xffff0000u;
    r.x = a.f; r.y = b.f;
    return r;
}
__device__ __forceinline__ unsigned f2bf2(float x, float y) {
    unsigned lo = (unsigned)__builtin_bit_cast(unsigned short, __float2bfloat16(x));
    unsigned hi = (unsigned)__builtin_bit_cast(unsigned short, __float2bfloat16(y));
    return lo | (hi << 16);
}

// ---------------------------------------------------------------------------
// Edge-index width detection (int64 vs int32 layout in the buffer).
// ---------------------------------------------------------------------------
__global__ void detect_kernel(const unsigned* __restrict__ e, int* __restrict__ flag) {
    __shared__ int nz;
    if (threadIdx.x == 0) nz = 0;
    __syncthreads();
    int local = 0;
    for (int i = threadIdx.x; i < 1024; i += blockDim.x)
        if (e[2 * i + 1] != 0) local = 1;
    if (local) atomicOr(&nz, 1);
    __syncthreads();
    if (threadIdx.x == 0) *flag = (nz == 0) ? 1 : 0;
}

__device__ __forceinline__ int edge_at(const unsigned* __restrict__ e, long idx, int is64) {
    return (int)(is64 ? e[2 * idx] : e[idx]);
}

__global__ void hist_kernel(const unsigned* __restrict__ e, const int* __restrict__ flag,
                            int* __restrict__ counts) {
    int i = blockIdx.x * blockDim.x + threadIdx.x;
    if (i >= N_EDGES) return;
    int is64 = *flag;
    int d = edge_at(e, (long)N_EDGES + i, is64);
    atomicAdd(&counts[d], 1);
}

__global__ void scan1_kernel(const int* __restrict__ counts, int* __restrict__ blockSums) {
    __shared__ int red[256];
    int base = blockIdx.x * 1024;
    int sum = 0;
    for (int i = threadIdx.x; i < 1024; i += 256) {
        int idx = base + i;
        sum += (idx < N_NODES) ? counts[idx] : 0;
    }
    red[threadIdx.x] = sum;
    __syncthreads();
    for (int s = 128; s > 0; s >>= 1) {
        if (threadIdx.x < s) red[threadIdx.x] += red[threadIdx.x + s];
        __syncthreads();
    }
    if (threadIdx.x == 0) blockSums[blockIdx.x] = red[0];
}

__global__ void scan2_kernel(int* __restrict__ blockSums, int nb, int* __restrict__ row_ptr) {
    int run = 0;
    for (int i = 0; i < nb; ++i) { int v = blockSums[i]; blockSums[i] = run; run += v; }
    row_ptr[N_NODES] = run;
}

__global__ void scan3_kernel(const int* __restrict__ counts, const int* __restrict__ blockSums,
                             int* __restrict__ row_ptr, int* __restrict__ cursor,
                             float* __restrict__ deg_inv) {
    __shared__ int lds[256];
    int base = blockIdx.x * 1024;
    int t = threadIdx.x;
    int v[4];
    int s = 0;
    for (int i = 0; i < 4; ++i) {
        int idx = base + t * 4 + i;
        v[i] = (idx < N_NODES) ? counts[idx] : 0;
        s += v[i];
    }
    lds[t] = s;
    __syncthreads();
    for (int off = 1; off < 256; off <<= 1) {
        int add = (t >= off) ? lds[t - off] : 0;
        __syncthreads();
        lds[t] += add;
        __syncthreads();
    }
    int excl = lds[t] - s + blockSums[blockIdx.x];
    for (int i = 0; i < 4; ++i) {
        int idx = base + t * 4 + i;
        if (idx < N_NODES) {
            row_ptr[idx] = excl;
            cursor[idx]  = excl;
            deg_inv[idx] = 1.0f / fmaxf((float)v[i], 1.0f);
            excl += v[i];
        }
    }
}

// ---------------------------------------------------------------------------
// fill v2: XCD-range-partitioned CSR scatter (full-line writebacks in one L2).
// ---------------------------------------------------------------------------
__global__ __launch_bounds__(256) void fill2_kernel(
    const unsigned* __restrict__ e, const int* __restrict__ flag,
    int* __restrict__ cursor, int* __restrict__ csr_src) {
    const int r     = blockIdx.x & (NXCD - 1);
    const int slice = blockIdx.x >> 3;
    const int lo = r * NRANGE;
    const int hi = min(lo + NRANGE, N_NODES);
    const int is64 = *flag;
    const int per = (N_EDGES + NSLICE - 1) / NSLICE;  // 6250
    const int i0 = slice * per;
    const int i1 = min(i0 + per, N_EDGES);
    for (int i = i0 + (int)threadIdx.x; i < i1; i += 256) {
        int d = edge_at(e, (long)N_EDGES + i, is64);
        if (d >= lo && d < hi) {
            int s = edge_at(e, (long)i, is64);
            int pos = atomicAdd(&cursor[d], 1);
            csr_src[pos] = s;
        }
    }
}

// ---------------------------------------------------------------------------
// Weight prep: BtAll[layer][768 rows][128 k] bf16, k-contiguous.
// Rows 0..383   (main):  n<128 -> W_lin col n ; n<384 -> W_film col n-128.
// Rows 384..767 (skip, PERMUTED in groups of 16):
//   rr=row-384, g=rr/16, within=rr%16, kind=g%3, c=(g/3)*16+within
//   kind 0 -> W_skip[:,c]; 1 -> W_fskip[:,c] (beta_s); 2 -> W_fskip[:,128+c] (gamma_s)
// ---------------------------------------------------------------------------
__global__ void bt_prep_kernel(const float* __restrict__ Wl, const float* __restrict__ Wf,
                               const float* __restrict__ Ws, const float* __restrict__ Wfs,
                               __hip_bfloat16* __restrict__ Bt) {
    int idx = blockIdx.x * 256 + threadIdx.x;
    if (idx >= 4 * 768 * 128) return;
    int k   = idx % 128;
    int row = (idx / 128) % 768;
    int lay = idx / (128 * 768);
    float w;
    if (row < 128) {
        w = Wl[(size_t)lay * 16384 + k * 128 + row];
    } else if (row < 384) {
        w = Wf[(size_t)lay * 32768 + k * 256 + (row - 128)];
    } else {
        int rr = row - 384;
        int g = rr >> 4, within = rr & 15;
        int kind = g % 3;
        int c = (g / 3) * 16 + within;
        if (kind == 0)      w = Ws [(size_t)lay * 16384 + k * 128 + c];
        else if (kind == 1) w = Wfs[(size_t)lay * 32768 + k * 256 + c];
        else                w = Wfs[(size_t)lay * 32768 + k * 256 + 128 + c];
    }
    Bt[idx] = __float2bfloat16(w);
}

// x (f32) -> A bf16 [node][128] (packed pairs)
__global__ void cast_kernel(const float* __restrict__ x, unsigned* __restrict__ A2) {
    long i = (long)blockIdx.x * 256 + threadIdx.x;
    if (i >= (long)N_NODES * 64) return;
    float2 v = ((const float2*)x)[i];
    A2[i] = f2bf2(v.x, v.y);
}

// ---------------------------------------------------------------------------
// Fused MFMA GEMM (round-6 structure + XCD-coscheduled siblings):
// block index swizzle: b = (mt%8) + 8*(jt + 7*(mt/8)) so all 7 jt-blocks of
// one m-tile land on the SAME XCD (xcd = b%8) consecutively -> the 32KB
// A-tile is fetched from L3 once and L2-hit by the other 6 siblings.
//  jt 0..2 : [h | beta | gamma] = A @ B rows 0..383   (128-wide n-tiles)
//  jt 3..6 : skb[node][c] = relu(gs*sk+bs) via permuted B rows 384..767
//            (96-wide n-tiles; wave = one (sk,bs,gs) triple), written bf16.
// ---------------------------------------------------------------------------
__global__ __launch_bounds__(256, 2) void fused_gemm_kernel(
    const __hip_bfloat16* __restrict__ A,
    const __hip_bfloat16* __restrict__ Bt,   // this layer, all 768 rows
    const float* __restrict__ bfilm,
    __hip_bfloat16* __restrict__ hbuf,       // [N][128]
    __hip_bfloat16* __restrict__ bgbuf,      // [N][256]
    __hip_bfloat16* __restrict__ skbh)       // [N][128] bf16 (relu'd skip)
{
    __shared__ alignas(16) unsigned char lds_raw[32768];
    unsigned char* ldsA = lds_raw;
    unsigned char* ldsB = lds_raw + 16384;

    const int b   = blockIdx.x;
    const int r8  = b & 7;
    const int q   = b >> 3;
    const int jt  = q % 7;
    const int mt  = (q / 7) * 8 + r8;
    if (mt >= MTILES) return;

    const int t  = threadIdx.x;
    const long node0 = (long)mt * 128;
    const int w  = t >> 6, l = t & 63;
    const int wm = w >> 1, wn = w & 1;
    const int lr = l & 15;
    const int kq16 = (l >> 4) << 4;
    const int sw = (lr & 7) << 4;

    const int sr  = t >> 3;
    const int scb = (t & 7) << 4;
    const int scbs = scb ^ ((sr & 7) << 4);

    const char* Abase = (const char*)A;

    if (jt < 3) {
        // ------------------- main path: 128-wide n-tile -------------------
        const char* Bbase = (const char*)Bt + (size_t)(jt * 128) * 256;
        f32x4 acc[4][4];
        #pragma unroll
        for (int mi = 0; mi < 4; ++mi)
            #pragma unroll
            for (int ni = 0; ni < 4; ++ni)
                #pragma unroll
                for (int j = 0; j < 4; ++j) acc[mi][ni][j] = 0.f;

        #pragma unroll
        for (int ks = 0; ks < 2; ++ks) {
            const int k0 = ks * 64;
            #pragma unroll
            for (int i = 0; i < 4; ++i) {
                const int r = (i << 5) + sr;
                gload16(Abase + (node0 + r) * 256 + (size_t)k0 * 2 + scbs,
                        ldsA + (((i << 8) + t) << 4));
                gload16(Bbase + (size_t)r * 256 + (size_t)k0 * 2 + scbs,
                        ldsB + (((i << 8) + t) << 4));
            }
            __syncthreads();

            #pragma unroll
            for (int kh = 0; kh < 2; ++kh) {
                const int kbs = ((kh << 6) + kq16) ^ sw;
                bf16x8 af[4], bfr[4];
                #pragma unroll
                for (int mi = 0; mi < 4; ++mi)
                    af[mi] = *(const bf16x8*)(ldsA + (wm * 64 + mi * 16 + lr) * 128 + kbs);
                #pragma unroll
                for (int ni = 0; ni < 4; ++ni)
                    bfr[ni] = *(const bf16x8*)(ldsB + (wn * 64 + ni * 16 + lr) * 128 + kbs);
                #pragma unroll
                for (int mi = 0; mi < 4; ++mi)
                    #pragma unroll
                    for (int ni = 0; ni < 4; ++ni)
                        acc[mi][ni] = __builtin_amdgcn_mfma_f32_16x16x32_bf16(
                            af[mi], bfr[ni], acc[mi][ni], 0, 0, 0);
            }
            __syncthreads();
        }

        const int col = lr;
        const int rb  = (l >> 4) << 2;
        if (jt == 0) {
            #pragma unroll
            for (int mi = 0; mi < 4; ++mi)
                #pragma unroll
                for (int ni = 0; ni < 4; ++ni) {
                    const int n = wn * 64 + ni * 16 + col;
                    #pragma unroll
                    for (int j = 0; j < 4; ++j) {
                        long node = node0 + wm * 64 + mi * 16 + rb + j;
                        if (node < N_NODES)
                            hbuf[node * 128 + n] = __float2bfloat16(acc[mi][ni][j]);
                    }
                }
        } else {
            const int c0 = (jt - 1) * 128;
            #pragma unroll
            for (int mi = 0; mi < 4; ++mi)
                #pragma unroll
                for (int ni = 0; ni < 4; ++ni) {
                    const int n = wn * 64 + ni * 16 + col;
                    const float bb = bfilm[c0 + n];
                    #pragma unroll
                    for (int j = 0; j < 4; ++j) {
                        long node = node0 + wm * 64 + mi * 16 + rb + j;
                        if (node < N_NODES)
                            bgbuf[node * 256 + c0 + n] = __float2bfloat16(acc[mi][ni][j] + bb);
                    }
                }
        }
    } else {
        // ------------------- skip path: 96-wide n-tile --------------------
        const int jt2 = jt - 3;
        const char* Bbase = (const char*)Bt + (size_t)(384 + jt2 * 96) * 256;
        f32x4 acc[4][3];
        #pragma unroll
        for (int mi = 0; mi < 4; ++mi)
            #pragma unroll
            for (int ni = 0; ni < 3; ++ni)
                #pragma unroll
                for (int j = 0; j < 4; ++j) acc[mi][ni][j] = 0.f;

        #pragma unroll
        for (int ks = 0; ks < 2; ++ks) {
            const int k0 = ks * 64;
            #pragma unroll
            for (int i = 0; i < 4; ++i) {
                const int r = (i << 5) + sr;
                gload16(Abase + (node0 + r) * 256 + (size_t)k0 * 2 + scbs,
                        ldsA + (((i << 8) + t) << 4));
            }
            #pragma unroll
            for (int i = 0; i < 3; ++i) {
                const int r = (i << 5) + sr;
                gload16(Bbase + (size_t)r * 256 + (size_t)k0 * 2 + scbs,
                        ldsB + (((i << 8) + t) << 4));
            }
            __syncthreads();

            #pragma unroll
            for (int kh = 0; kh < 2; ++kh) {
                const int kbs = ((kh << 6) + kq16) ^ sw;
                bf16x8 af[4], bfr[3];
                #pragma unroll
                for (int mi = 0; mi < 4; ++mi)
                    af[mi] = *(const bf16x8*)(ldsA + (wm * 64 + mi * 16 + lr) * 128 + kbs);
                #pragma unroll
                for (int ni = 0; ni < 3; ++ni)
                    bfr[ni] = *(const bf16x8*)(ldsB + (wn * 48 + ni * 16 + lr) * 128 + kbs);
                #pragma unroll
                for (int mi = 0; mi < 4; ++mi)
                    #pragma unroll
                    for (int ni = 0; ni < 3; ++ni)
                        acc[mi][ni] = __builtin_amdgcn_mfma_f32_16x16x32_bf16(
                            af[mi], bfr[ni], acc[mi][ni], 0, 0, 0);
            }
            __syncthreads();
        }

        // fused FiLM epilogue: ni 0=sk, 1=bs, 2=gs for the SAME column c
        const int c  = (2 * jt2 + wn) * 16 + lr;
        const int rb = (l >> 4) << 2;
        #pragma unroll
        for (int mi = 0; mi < 4; ++mi)
            #pragma unroll
            for (int j = 0; j < 4; ++j) {
                long node = node0 + wm * 64 + mi * 16 + rb + j;
                if (node < N_NODES) {
                    float o = fmaxf(acc[mi][2][j] * acc[mi][0][j] + acc[mi][1][j], 0.f);
                    skbh[node * 128 + c] = __float2bfloat16(o);
                }
            }
    }
}

// ---------------------------------------------------------------------------
// Aggregation v4: 1 wave per node; lane owns 4 cols (uint2 = 8 B gather);
// half-waves process two edges per gather instruction; 8 pairs unrolled
// (16 edges / 8 gathers in flight). 32-bit offsets; shfl_xor(32) reduce.
// ---------------------------------------------------------------------------
__global__ __launch_bounds__(256) void agg_kernel(
    const uint2* __restrict__ h22,      // hbuf  as [N][32] uint2
    const uint2* __restrict__ bgu2,     // bgbuf as [N][64] uint2 (beta 0..31 | gamma 32..63)
    const int* __restrict__ row_ptr, const int* __restrict__ csr_src,
    const float* __restrict__ deg_inv,
    const uint2* __restrict__ sku2,     // skb as [N][32] uint2 (bf16, relu'd)
    uint2* __restrict__ An2,            // next A as [N][32] uint2 (bf16)
    float4* __restrict__ fo4)           // final out as [N][32] float4
{
    const int t = threadIdx.x;
    const int v = blockIdx.x * 4 + (t >> 6);
    const int l = t & 63;
    const int half = l >> 5;
    const unsigned c = l & 31;

    const uint2 bu = bgu2[(size_t)v * 64 + c];
    const uint2 gu = bgu2[(size_t)v * 64 + 32 + c];
    const float2 be01 = bf2f(bu.x), be23 = bf2f(bu.y);
    const float2 ga01 = bf2f(gu.x), ga23 = bf2f(gu.y);
    const float dinv = deg_inv[v];

    const int b = row_ptr[v];
    const int e = row_ptr[v + 1];
    const int ne = e - b;
    const int npair = ne >> 1;

    f32x4 ac0 = {0,0,0,0}, ac1 = {0,0,0,0}, ac2 = {0,0,0,0}, ac3 = {0,0,0,0};

    const int* cp = csr_src + b + half;   // this lane's edge stream (stride 2)

#define ACC(A_, P_) do {                                   \
        float2 h01 = bf2f((P_).x), h23 = bf2f((P_).y);     \
        (A_)[0] += fmaxf(ga01.x * h01.x + be01.x, 0.f);    \
        (A_)[1] += fmaxf(ga01.y * h01.y + be01.y, 0.f);    \
        (A_)[2] += fmaxf(ga23.x * h23.x + be23.x, 0.f);    \
        (A_)[3] += fmaxf(ga23.y * h23.y + be23.y, 0.f);    \
    } while (0)

    int pi = 0;
    for (; pi + 8 <= npair; pi += 8) {
        unsigned s[8];
        uint2 p[8];
        #pragma unroll
        for (int u = 0; u < 8; ++u) s[u] = (unsigned)cp[2 * (pi + u)];
        #pragma unroll
        for (int u = 0; u < 8; ++u) p[u] = h22[s[u] * 32u + c];
        ACC(ac0, p[0]); ACC(ac1, p[1]); ACC(ac2, p[2]); ACC(ac3, p[3]);
        ACC(ac0, p[4]); ACC(ac1, p[5]); ACC(ac2, p[6]); ACC(ac3, p[7]);
    }
    for (; pi + 4 <= npair; pi += 4) {
        unsigned s[4];
        uint2 p[4];
        #pragma unroll
        for (int u = 0; u < 4; ++u) s[u] = (unsigned)cp[2 * (pi + u)];
        #pragma unroll
        for (int u = 0; u < 4; ++u) p[u] = h22[s[u] * 32u + c];
        ACC(ac0, p[0]); ACC(ac1, p[1]); ACC(ac2, p[2]); ACC(ac3, p[3]);
    }
    for (; pi < npair; ++pi) {
        const unsigned s0 = (unsigned)cp[2 * pi];
        const uint2 p0 = h22[s0 * 32u + c];
        ACC(ac0, p0);
    }
    if ((ne & 1) && half == 0) {
        const unsigned s0 = (unsigned)csr_src[e - 1];
        const uint2 p0 = h22[s0 * 32u + c];
        ACC(ac1, p0);
    }
#undef ACC

    float r0 = (ac0[0] + ac1[0]) + (ac2[0] + ac3[0]);
    float r1 = (ac0[1] + ac1[1]) + (ac2[1] + ac3[1]);
    float r2 = (ac0[2] + ac1[2]) + (ac2[2] + ac3[2]);
    float r3 = (ac0[3] + ac1[3]) + (ac2[3] + ac3[3]);
    r0 += __shfl_xor(r0, 32);
    r1 += __shfl_xor(r1, 32);
    r2 += __shfl_xor(r2, 32);
    r3 += __shfl_xor(r3, 32);

    const uint2 sk = sku2[(size_t)v * 32 + c];
    const float2 s01 = bf2f(sk.x), s23 = bf2f(sk.y);
    const float o0 = s01.x + r0 * dinv;
    const float o1 = s01.y + r1 * dinv;
    const float o2 = s23.x + r2 * dinv;
    const float o3 = s23.y + r3 * dinv;

    if (half == 0) {
        if (An2) {
            An2[(size_t)v * 32 + c] = make_uint2(f2bf2(o0, o1), f2bf2(o2, o3));
        } else {
            fo4[(size_t)v * 32 + c] = make_float4(o0, o1, o2, o3);
        }
    }
}

// ---------------------------------------------------------------------------
extern "C" void kernel_launch(void* const* d_in, const int* in_sizes, int n_in,
                              void* d_out, int out_size, void* d_ws, size_t ws_size,
                              hipStream_t stream) {
    const float*    x_in    = (const float*)d_in[0];
    const unsigned* eidx    = (const unsigned*)d_in[1];
    const float*    W_lin   = (const float*)d_in[2];
    const float*    W_film  = (const float*)d_in[3];
    const float*    b_film  = (const float*)d_in[4];
    const float*    W_skip  = (const float*)d_in[5];
    const float*    W_fskip = (const float*)d_in[6];
    float*          out     = (float*)d_out;

    char* ws = (char*)d_ws;
    size_t off = 0;
    auto alloc = [&](size_t bytes) -> void* {
        void* p = ws + off;
        off = (off + bytes + 255) & ~(size_t)255;
        return p;
    };
    int*   flag      = (int*)alloc(4);
    int*   counts    = (int*)alloc((size_t)N_NODES * 4);
    int*   row_ptr   = (int*)alloc((size_t)(N_NODES + 1) * 4);
    int*   cursor    = (int*)alloc((size_t)N_NODES * 4);
    int*   blockSums = (int*)alloc(128 * 4);
    float* deg_inv   = (float*)alloc((size_t)N_NODES * 4);
    int*   csr_src   = (int*)alloc((size_t)N_EDGES * 4);
    __hip_bfloat16* Abuf  = (__hip_bfloat16*)alloc((size_t)N_PAD * 128 * 2);
    __hip_bfloat16* BtAll = (__hip_bfloat16*)alloc((size_t)4 * 768 * 128 * 2);
    __hip_bfloat16* hbuf  = (__hip_bfloat16*)alloc((size_t)N_NODES * 128 * 2);
    __hip_bfloat16* bgbuf = (__hip_bfloat16*)alloc((size_t)N_NODES * 256 * 2);
    __hip_bfloat16* skbh  = (__hip_bfloat16*)alloc((size_t)N_NODES * 128 * 2);
    (void)ws_size; (void)in_sizes; (void)n_in; (void)out_size;

    const int NB_SCAN = (N_NODES + 1023) / 1024; // 98
    const int EB = (N_EDGES + 255) / 256;        // 6250

    hipMemsetAsync(counts, 0, (size_t)N_NODES * 4, stream);
    detect_kernel<<<1, 256, 0, stream>>>(eidx, flag);
    hist_kernel<<<EB, 256, 0, stream>>>(eidx, flag, counts);
    scan1_kernel<<<NB_SCAN, 256, 0, stream>>>(counts, blockSums);
    scan2_kernel<<<1, 1, 0, stream>>>(blockSums, NB_SCAN, row_ptr);
    scan3_kernel<<<NB_SCAN, 256, 0, stream>>>(counts, blockSums, row_ptr, cursor, deg_inv);
    fill2_kernel<<<NXCD * NSLICE, 256, 0, stream>>>(eidx, flag, cursor, csr_src);

    cast_kernel<<<(N_NODES * 64 + 255) / 256, 256, 0, stream>>>(x_in, (unsigned*)Abuf);
    bt_prep_kernel<<<(4 * 768 * 128 + 255) / 256, 256, 0, stream>>>(
        W_lin, W_film, W_skip, W_fskip, BtAll);

    const int AGG_B = N_NODES / 4; // 25000
    for (int l = 0; l < 4; ++l) {
        const __hip_bfloat16* Bt_l = BtAll + (size_t)l * 768 * 128;
        fused_gemm_kernel<<<GEMM_GRID, 256, 0, stream>>>(
            Abuf, Bt_l, b_film + (size_t)l * 256, hbuf, bgbuf, skbh);
        agg_kernel<<<AGG_B, 256, 0, stream>>>(
            (const uint2*)hbuf, (const uint2*)bgbuf,
            row_ptr, csr_src, deg_inv, (const uint2*)skbh,
            (l < 3) ? (uint2*)Abuf : (uint2*)nullptr,
            (l == 3) ? (float4*)out : (float4*)nullptr);
    }
}